// Round 6
// baseline (142.253 us; speedup 1.0000x reference)
//
#include <hip/hip_runtime.h>
#include <math.h>

// Problem constants (match reference)
#define N_ATOMS 256
#define N_FEAT  128
#define BATCH   8
#define BINS    300
#define INV_STEP 149.5f        // 1/STEP, STEP = 2/(BINS-1)
#define ONE_OVER_2PI 0.15915494309189535f
#define INV_112 0.8928571428571429f   // 1/1.12
#define WIN 6                  // RBF window radius: exp(-36) ~ 2e-16, below f32 noise
#define WINW (2*WIN+1)
#define NHIST 8                // privatized histogram copies

struct V3 { float x, y, z; };
__device__ __forceinline__ V3 v3sub(V3 a, V3 b) { return {a.x-b.x, a.y-b.y, a.z-b.z}; }
__device__ __forceinline__ float v3dot(V3 a, V3 b) { return a.x*b.x + a.y*b.y + a.z*b.z; }
__device__ __forceinline__ V3 v3cross(V3 a, V3 b) {
    return {a.y*b.z - a.z*b.y, a.z*b.x - a.x*b.z, a.x*b.y - a.y*b.x};
}
__device__ __forceinline__ V3 v3nrm(V3 a) {
    float r = __builtin_amdgcn_rsqf(v3dot(a, a));   // v_rsq_f32
    return {a.x*r, a.y*r, a.z*r};
}
__device__ __forceinline__ float clamp1(float x) { return fminf(1.0f, fmaxf(-1.0f, x)); }

// Branchless Cephes asinf: |x|<=0.5 poly; else pi/2 - 2*asin(sqrt((1-|x|)/2)).
__device__ __forceinline__ float asin_fast(float x) {
    float u = fabsf(x);
    bool big = u > 0.5f;
    float z = big ? 0.5f * (1.0f - u) : u * u;
    float s = big ? __builtin_amdgcn_sqrtf(z) : u;  // v_sqrt_f32
    float p = fmaf(z, 4.2163199048e-2f, 2.4181311049e-2f);
    p = fmaf(z, p, 4.5470025998e-2f);
    p = fmaf(z, p, 7.4953002686e-2f);
    p = fmaf(z, p, 1.6666752422e-1f);
    float r = fmaf(s * z, p, s);                   // asin on reduced arg
    r = big ? (1.5707963267948966f - 2.0f * r) : r;
    return copysignf(r, x);
}

// writhe of segment pair (i,i+1),(j,j+1) from LDS coords
__device__ __forceinline__ float writhe_ij(const float* cs, int i, int j) {
    V3 pi  = {cs[i*3+0],     cs[i*3+1],     cs[i*3+2]};
    V3 pi1 = {cs[(i+1)*3+0], cs[(i+1)*3+1], cs[(i+1)*3+2]};
    V3 pj  = {cs[j*3+0],     cs[j*3+1],     cs[j*3+2]};
    V3 pj1 = {cs[(j+1)*3+0], cs[(j+1)*3+1], cs[(j+1)*3+2]};

    V3 d0 = v3nrm(v3sub(pj,  pi));
    V3 d1 = v3nrm(v3sub(pj1, pi));
    V3 d2 = v3nrm(v3sub(pj,  pi1));
    V3 d3 = v3nrm(v3sub(pj1, pi1));

    V3 c0 = v3nrm(v3cross(d0, d1));
    V3 c1 = v3nrm(v3cross(d1, d3));
    V3 c2 = v3nrm(v3cross(d3, d2));
    V3 c3 = v3nrm(v3cross(d2, d0));

    float omega = asin_fast(clamp1(v3dot(c0, c1)))
                + asin_fast(clamp1(v3dot(c1, c2)))
                + asin_fast(clamp1(v3dot(c2, c3)))
                + asin_fast(clamp1(v3dot(c3, c0)));

    float sg = v3dot(v3cross(v3sub(pj1, pj), v3sub(pi1, pi)), d0);
    float sign = (sg > 0.0f) ? 1.0f : ((sg < 0.0f) ? -1.0f : 0.0f);
    return omega * sign * ONE_OVER_2PI;
}

// One block per node n = b*256 + t. Incoming edges of node t: a in [0, t-2];
// type-1 (start-pair, segment (a,t)) exists iff t<=254; type-2 (end-pair,
// segment (a-1,t-1)) exists iff a>=1. Both share g = exp(-||c_a - c_t||^2).
// Writhe values are recomputed in-block from LDS coords (no wr workspace).
__global__ __launch_bounds__(256) void fused_kernel(const float* __restrict__ coords,
                                                    const float* __restrict__ nf,
                                                    const float* __restrict__ basis,
                                                    float* __restrict__ out) {
    const int n = blockIdx.x;
    const int b = n >> 8;
    const int t = n & 255;
    const int tid = threadIdx.x;

    if (t < 2) {  // whole block uniform branch, before any barrier
        if (tid < N_FEAT) out[n * N_FEAT + tid] = nf[n * N_FEAT + tid];
        return;
    }

    __shared__ float cs[N_ATOMS * 3];      // 3 KB
    __shared__ float h8[NHIST * BINS];     // 9.6 KB
    __shared__ float part4[4 * N_FEAT];    // 2 KB
    __shared__ float sden;
    __shared__ int skmin, skmax;

    for (int idx = tid; idx < N_ATOMS * 3; idx += 256)
        cs[idx] = coords[(b << 8) * 3 + idx];
    for (int k = tid; k < NHIST * BINS; k += 256) h8[k] = 0.0f;
    if (tid == 0) { sden = 0.0f; skmin = BINS; skmax = -1; }
    __syncthreads();

    const int a = tid;
    float dpart = 0.0f;
    if (a <= t - 2) {
        float dx = cs[a*3+0] - cs[t*3+0];
        float dy = cs[a*3+1] - cs[t*3+1];
        float dz = cs[a*3+2] - cs[t*3+2];
        float g = __expf(-(dx*dx + dy*dy + dz*dz));
        const bool e1 = (t <= N_ATOMS - 2);
        dpart = g * ((e1 ? 1.0f : 0.0f) + (a >= 1 ? 1.0f : 0.0f));

        const int copy = tid & (NHIST - 1);
        const int rot = tid % WINW;
        #pragma unroll
        for (int typ = 0; typ < 2; ++typ) {
            bool do_it = (typ == 0) ? e1 : (a >= 1);
            if (do_it) {
                float w = (typ == 0) ? writhe_ij(cs, a, t)
                                     : writhe_ij(cs, a - 1, t - 1);
                float p = (w + 1.0f) * INV_STEP;   // p - k = (w - c_k)/STEP
                int k0 = __float2int_rn(p);
                atomicMin(&skmin, max(0, k0 - WIN));
                atomicMax(&skmax, min(BINS - 1, k0 + WIN));
                int klo = k0 - WIN;
                #pragma unroll
                for (int m = 0; m < WINW; ++m) {
                    int mm = m + rot; if (mm >= WINW) mm -= WINW;
                    int k = klo + mm;
                    if (k >= 0 && k < BINS) {
                        float d = p - (float)k;
                        atomicAdd(&h8[copy * BINS + k], g * __expf(-d * d));
                    }
                }
            }
        }
    }
    // denominator: wave-reduce then one LDS atomic per wave
    for (int off = 32; off > 0; off >>= 1) dpart += __shfl_down(dpart, off);
    if ((tid & 63) == 0) atomicAdd(&sden, dpart);
    __syncthreads();

    // reduce privatized copies into h8[0..BINS)
    for (int k = tid; k < BINS; k += 256) {
        float s = h8[k];
        #pragma unroll
        for (int c = 1; c < NHIST; ++c) s += h8[c * BINS + k];
        h8[k] = s;
    }
    __syncthreads();

    // projection over the touched bin range only; 4 bin-quarters x 64 feat-pairs
    const int kmin = skmin;
    const int len = skmax - kmin + 1;          // >=1 (t>=2 guarantees a deposit)
    const int chunk = (len + 3) >> 2;
    const int q = tid >> 6;
    const int fq = tid & 63;
    int ks = kmin + q * chunk;
    int ke = min(ks + chunk, kmin + len);
    const float2* b2 = reinterpret_cast<const float2*>(basis);
    float ax = 0.0f, ay = 0.0f;
    for (int k = ks; k < ke; ++k) {
        float hv = h8[k];
        float2 bv = b2[k * (N_FEAT / 2) + fq];
        ax = fmaf(hv, bv.x, ax);
        ay = fmaf(hv, bv.y, ay);
    }
    part4[q * N_FEAT + 2 * fq]     = ax;
    part4[q * N_FEAT + 2 * fq + 1] = ay;
    __syncthreads();

    if (tid < N_FEAT) {
        float s = part4[tid] + part4[N_FEAT + tid]
                + part4[2 * N_FEAT + tid] + part4[3 * N_FEAT + tid];
        out[n * N_FEAT + tid] = nf[n * N_FEAT + tid] + s * (INV_112 / sden);
    }
}

extern "C" void kernel_launch(void* const* d_in, const int* in_sizes, int n_in,
                              void* d_out, int out_size, void* d_ws, size_t ws_size,
                              hipStream_t stream) {
    const float* coords = (const float*)d_in[0];   // (B*N, 3) f32
    const float* nf     = (const float*)d_in[1];   // (B*N, 128) f32
    const float* basis  = (const float*)d_in[2];   // (300, 128) f32
    float* out = (float*)d_out;                    // (B*N, 128) f32

    fused_kernel<<<BATCH * N_ATOMS, 256, 0, stream>>>(coords, nf, basis, out);
}